// Round 16
// baseline (781.614 us; speedup 1.0000x reference)
//
#include <hip/hip_runtime.h>
#include <hip/hip_bf16.h>
#include <math.h>

#define NN 1024
#define EMB 128
#define FC 512
#define NEDGE 523776   // 1024*1023/2
#define BM 128         // edge rows per block; 4092 blocks

typedef __attribute__((ext_vector_type(16))) float f32x16;
typedef __attribute__((ext_vector_type(8))) short bf16x8;
typedef __attribute__((ext_vector_type(4))) unsigned int u32x4;
typedef __attribute__((ext_vector_type(8))) int i32x8;

__device__ __forceinline__ float bf2f(unsigned short u) {
  union { unsigned int i; float f; } v; v.i = ((unsigned int)u) << 16; return v.f;
}
__device__ __forceinline__ unsigned short f2bf(float f) {
  return __builtin_bit_cast(unsigned short, __float2bfloat16(f));
}
__device__ __forceinline__ int cum_edges(int i) { return i * NN - ((i * (i + 1)) >> 1); }

// pack 4 f32 -> 4 fp8(e4m3 OCP) in one dword (bytes in order a,b,c,d)
__device__ __forceinline__ unsigned int pk4_fp8(float a, float b, float c, float d) {
  int v = __builtin_amdgcn_cvt_pk_fp8_f32(a, b, 0, false);
  v = __builtin_amdgcn_cvt_pk_fp8_f32(c, d, v, true);
  return (unsigned int)v;
}
// fp8 MFMA 32x32 K=64, uniform pow2 descale folded into the scale operand.
// L0: s=-9  (0x76...)  acc = 2^7 * preact  (o0 fp8 convention)
// L1: s=-13 (0x72...)  acc = true preact
#define MFMA32_L0(A,B,C) __builtin_amdgcn_mfma_scale_f32_32x32x64_f8f6f4((A),(B),(C),0,0,0,0x76767676,0,0x7f7f7f7f)
#define MFMA32_L1(A,B,C) __builtin_amdgcn_mfma_scale_f32_32x32x64_f8f6f4((A),(B),(C),0,0,0,0x72727272,0,0x7f7f7f7f)

// ---------------- setup kernels (tiny) ----------------
// fp8 weight tiles (x2^6) for 32x32x64 frags: lane holds row=lane&31,
// k-window = (lane>>5)*32 + [0..32) contiguous bytes.
// W0 dword d = wv*2048 + kb*1024 + f*512 + lane*8 + dw   (kb<2, f<2)
// W1 dword d = wv*8192 + kb*1024 + f*512 + lane*8 + dw   (kb<8, f<2)
__global__ void k_cvt_weights(const float* __restrict__ lw0, const float* __restrict__ lw1,
                              unsigned int* __restrict__ w0q, unsigned int* __restrict__ w1q) {
  int d = blockIdx.x * 256 + threadIdx.x;   // 320 blocks * 256 = 81920 dwords exact
  if (d < 16384) {
    int dw = d & 7, lane = (d >> 3) & 63, f = (d >> 9) & 1, kb = (d >> 10) & 1, wv = (d >> 11) & 7;
    int fc = wv*64 + f*32 + (lane & 31);
    int k  = kb*64 + (lane >> 5)*32 + dw*4;
    float4 s = *(const float4*)(lw0 + fc*EMB + k);
    w0q[d] = pk4_fp8(s.x*64.f, s.y*64.f, s.z*64.f, s.w*64.f);
  } else {
    int u = d - 16384;
    int dw = u & 7, lane = (u >> 3) & 63, f = (u >> 9) & 1, kb = (u >> 10) & 7, wv = (u >> 13) & 7;
    int fc = wv*64 + f*32 + (lane & 31);
    int k  = kb*64 + (lane >> 5)*32 + dw*4;
    float4 s = *(const float4*)(lw1 + fc*FC + k);
    w1q[u] = pk4_fp8(s.x*64.f, s.y*64.f, s.z*64.f, s.w*64.f);
  }
}

__global__ void k_mean_x(const float* __restrict__ x, float* __restrict__ mean0) {
  __shared__ float sx[256], sy[256];
  float ax = 0.f, ay = 0.f;
  for (int i = threadIdx.x; i < NN; i += 256) { ax += x[2*i]; ay += x[2*i+1]; }
  sx[threadIdx.x] = ax; sy[threadIdx.x] = ay;
  __syncthreads();
  for (int st = 128; st > 0; st >>= 1) {
    if (threadIdx.x < st) { sx[threadIdx.x] += sx[threadIdx.x+st]; sy[threadIdx.x] += sy[threadIdx.x+st]; }
    __syncthreads();
  }
  if (threadIdx.x == 0) { mean0[0] = sx[0] * (1.f/NN); mean0[1] = sy[0] * (1.f/NN); }
}

__global__ void k_sage0(const float* __restrict__ x, const float* __restrict__ wrel,
                        const float* __restrict__ brel, const float* __restrict__ wroot,
                        const float* __restrict__ mean0, float* __restrict__ h0) {
  int idx = blockIdx.x * 256 + threadIdx.x;
  int i = idx >> 7, c = idx & 127;
  float v = mean0[0]*wrel[2*c] + mean0[1]*wrel[2*c+1] + brel[c]
          + x[2*i]*wroot[2*c] + x[2*i+1]*wroot[2*c+1];
  h0[idx] = fmaxf(v, 0.f);
}

__global__ void k_mean_h0(const float* __restrict__ h0, float* __restrict__ mean1) {
  __shared__ float s[256];
  int c = blockIdx.x;
  float a = 0.f;
  for (int i = threadIdx.x; i < NN; i += 256) a += h0[i*EMB + c];
  s[threadIdx.x] = a;
  __syncthreads();
  for (int st = 128; st > 0; st >>= 1) {
    if (threadIdx.x < st) s[threadIdx.x] += s[threadIdx.x+st];
    __syncthreads();
  }
  if (threadIdx.x == 0) mean1[c] = s[0] * (1.f/NN);
}

__global__ void k_relc(const float* __restrict__ mean1, const float* __restrict__ wrel1,
                       const float* __restrict__ brel1, float* __restrict__ relc) {
  int c = threadIdx.x;
  float a = brel1[c];
  #pragma unroll 8
  for (int k = 0; k < EMB; ++k) a += mean1[k] * wrel1[c*EMB + k];
  relc[c] = a;
}

// hb pre-scaled by 32 -> edge products carry 2^10
__global__ void k_sage1(const float* __restrict__ h0, const float* __restrict__ wroot1,
                        const float* __restrict__ relc, unsigned short* __restrict__ hb) {
  int idx = blockIdx.x * 256 + threadIdx.x;
  int i = idx >> 7, c = idx & 127;
  const float4* hr = (const float4*)(h0 + i*EMB);
  const float4* wr = (const float4*)(wroot1 + c*EMB);
  float a = relc[c];
  #pragma unroll 8
  for (int k = 0; k < EMB/4; ++k) {
    float4 h = hr[k], w = wr[k];
    a += h.x*w.x + h.y*w.y + h.z*w.z + h.w*w.w;
  }
  hb[idx] = f2bf(fmaxf(a, 0.f) * 32.0f);
}

// ---------------- fused edge MLP (full fp8, 32x32x64 MFMA, BM=128) --------
// 8 waves; wave w owns fc slice [w*64, w*64+64): 2 m-tiles of 32, f-split.
// Edges 128: 4 n-tiles of 32. A = weights (m=fc), B = activations (n=edge).
// D (32x32): col(edge)=lane&31, row(fc_local)=(rg&3)+8*(rg>>2)+4*(lane>>5).
// BM=128 halves round count (8 rounds) and per-edge weight-L2 traffic.
// Both layers f-split so per-pass acc = 4x f32x16 (64 regs) -> no spill.
// LDS split-half layout (16B lane stride, conflict-minimal).
// Scales: e=2^10, W=2^6, o0=2^7; descales folded into MFMA scale operand.
// LDS 80KB; (512,4) -> 2 blocks/CU (r2/r3 measured 2x80KB co-residency).
__global__ __launch_bounds__(512, 4)
void k_edge_mlp(const unsigned short* __restrict__ hb,
                const unsigned int* __restrict__ w0q,
                const float* __restrict__ lb0,
                const unsigned int* __restrict__ w1q,
                const float* __restrict__ lb1,
                const float* __restrict__ lw2,
                const float* __restrict__ lb2,
                float* __restrict__ out) {
  __shared__ __align__(16) unsigned int e_lds[4096];    // 16 KB [et4][kb2][half2][lane64][16B]
  __shared__ __align__(16) unsigned int o0_lds[16384];  // 64 KB [et4][kb8][half2][lane64][16B]

  const int tid  = threadIdx.x;
  const int lane = tid & 63;
  const int wv   = tid >> 6;           // 0..7
  const int l31  = lane & 31;
  const int hi   = lane >> 5;
  const int blk  = blockIdx.x;
  const int fcb  = wv * 64;

  const char* w0w = (const char*)w0q + wv * 8192;    // 8 KB/wave
  const char* w1w = (const char*)w1q + wv * 32768;   // 32 KB/wave

  // ---- Phase A: gather h rows, build e tile (fp8, split-half frag order) ----
  {
    int r = tid >> 2;                  // edge row 0..127
    int c4 = tid & 3;                  // which 32-element chunk of the row
    int k = blk * BM + r;
    float s = sqrtf((float)(4190209 - 8*k));           // (2N-1)^2 - 8k
    int i = (int)((2047.0f - s) * 0.5f);
    if (i < 0) i = 0;
    if (i > NN-2) i = NN-2;
    if (cum_edges(i+1) <= k) ++i;
    if (cum_edges(i+1) <= k) ++i;
    if (cum_edges(i) > k) --i;
    if (cum_edges(i) > k) --i;
    int j = k - cum_edges(i) + i + 1;
    const bf16x8* hi8 = (const bf16x8*)(hb + i*EMB + c4*32);
    const bf16x8* hj8 = (const bf16x8*)(hb + j*EMB + c4*32);
    // dest: et=r>>5, kb=c4>>1, khigh=c4&1, half=g, lane'=khigh*32+(r&31)
    int base = (r>>5)*4096 + (c4>>1)*2048 + ((c4&1)*32 + (r&31))*16;
    #pragma unroll
    for (int g = 0; g < 2; ++g) {
      bf16x8 a0 = hi8[g*2], a1 = hi8[g*2+1];
      bf16x8 b0 = hj8[g*2], b1 = hj8[g*2+1];
      float p[16];
      #pragma unroll
      for (int u = 0; u < 8; ++u) {
        p[u]   = bf2f((unsigned short)a0[u]) * bf2f((unsigned short)b0[u]);
        p[8+u] = bf2f((unsigned short)a1[u]) * bf2f((unsigned short)b1[u]);
      }
      u32x4 d;
      #pragma unroll
      for (int u = 0; u < 4; ++u)
        d[u] = pk4_fp8(p[4*u], p[4*u+1], p[4*u+2], p[4*u+3]);
      *(u32x4*)((char*)e_lds + base + g*1024) = d;
    }
  }
  __syncthreads();

  // ---- Layer0: K=128 = 2 kb of 64; f-split; acc init = b0 * 2^7 ----
  {
    const char* rbe = (const char*)e_lds + lane*16;
    char* ob = (char*)o0_lds + wv*2048 + l31*16 + hi*4;
    #pragma unroll
    for (int f = 0; f < 2; ++f) {
      f32x16 acc[4];
      #pragma unroll
      for (int t = 0; t < 4; ++t) {
        float4 bv = *(const float4*)(lb0 + fcb + f*32 + t*8 + hi*4);
        #pragma unroll
        for (int e = 0; e < 4; ++e) {
          acc[e][4*t+0] = bv.x*128.f; acc[e][4*t+1] = bv.y*128.f;
          acc[e][4*t+2] = bv.z*128.f; acc[e][4*t+3] = bv.w*128.f;
        }
      }
      #pragma unroll
      for (int kb = 0; kb < 2; ++kb) {
        i32x8 aw = *(const i32x8*)(w0w + (kb*2+f)*2048 + lane*32);
        i32x8 b0, b1, b2, b3;
        *(u32x4*)&b0       = *(const u32x4*)(rbe + 0*4096 + kb*2048);
        *((u32x4*)&b0 + 1) = *(const u32x4*)(rbe + 0*4096 + kb*2048 + 1024);
        *(u32x4*)&b1       = *(const u32x4*)(rbe + 1*4096 + kb*2048);
        *((u32x4*)&b1 + 1) = *(const u32x4*)(rbe + 1*4096 + kb*2048 + 1024);
        *(u32x4*)&b2       = *(const u32x4*)(rbe + 2*4096 + kb*2048);
        *((u32x4*)&b2 + 1) = *(const u32x4*)(rbe + 2*4096 + kb*2048 + 1024);
        *(u32x4*)&b3       = *(const u32x4*)(rbe + 3*4096 + kb*2048);
        *((u32x4*)&b3 + 1) = *(const u32x4*)(rbe + 3*4096 + kb*2048 + 1024);
        __builtin_amdgcn_s_setprio(1);
        acc[0] = MFMA32_L0(aw, b0, acc[0]);
        acc[1] = MFMA32_L0(aw, b1, acc[1]);
        acc[2] = MFMA32_L0(aw, b2, acc[2]);
        acc[3] = MFMA32_L0(aw, b3, acc[3]);
        __builtin_amdgcn_s_setprio(0);
      }
      // relu + fp8 o0 store for this f-pass (acc already at 2^7 scale)
      #pragma unroll
      for (int e = 0; e < 4; ++e)
        #pragma unroll
        for (int t = 0; t < 4; ++t) {
          unsigned int d = pk4_fp8(fmaxf(acc[e][4*t+0], 0.f),
                                   fmaxf(acc[e][4*t+1], 0.f),
                                   fmaxf(acc[e][4*t+2], 0.f),
                                   fmaxf(acc[e][4*t+3], 0.f));
          *(unsigned int*)(ob + e*16384 + (t>>1)*1024 + f*512 + (t&1)*8) = d;
        }
    }
  }
  __syncthreads();

  // ---- Layer1: K=512 = 8 kb of 64; f-split; acc init = b1 (true scale) ----
  float rs[4] = {0.f, 0.f, 0.f, 0.f};
  {
    const char* rbo = (const char*)o0_lds + lane*16;
    #pragma unroll
    for (int f = 0; f < 2; ++f) {
      f32x16 acc[4];
      #pragma unroll
      for (int t = 0; t < 4; ++t) {
        float4 bv = *(const float4*)(lb1 + fcb + f*32 + t*8 + hi*4);
        #pragma unroll
        for (int e = 0; e < 4; ++e) {
          acc[e][4*t+0] = bv.x; acc[e][4*t+1] = bv.y;
          acc[e][4*t+2] = bv.z; acc[e][4*t+3] = bv.w;
        }
      }
      #pragma unroll
      for (int kb = 0; kb < 8; ++kb) {
        i32x8 aw = *(const i32x8*)(w1w + (kb*2+f)*2048 + lane*32);
        i32x8 b0, b1, b2, b3;
        *(u32x4*)&b0       = *(const u32x4*)(rbo + 0*16384 + kb*2048);
        *((u32x4*)&b0 + 1) = *(const u32x4*)(rbo + 0*16384 + kb*2048 + 1024);
        *(u32x4*)&b1       = *(const u32x4*)(rbo + 1*16384 + kb*2048);
        *((u32x4*)&b1 + 1) = *(const u32x4*)(rbo + 1*16384 + kb*2048 + 1024);
        *(u32x4*)&b2       = *(const u32x4*)(rbo + 2*16384 + kb*2048);
        *((u32x4*)&b2 + 1) = *(const u32x4*)(rbo + 2*16384 + kb*2048 + 1024);
        *(u32x4*)&b3       = *(const u32x4*)(rbo + 3*16384 + kb*2048);
        *((u32x4*)&b3 + 1) = *(const u32x4*)(rbo + 3*16384 + kb*2048 + 1024);
        __builtin_amdgcn_s_setprio(1);
        acc[0] = MFMA32_L1(aw, b0, acc[0]);
        acc[1] = MFMA32_L1(aw, b1, acc[1]);
        acc[2] = MFMA32_L1(aw, b2, acc[2]);
        acc[3] = MFMA32_L1(aw, b3, acc[3]);
        __builtin_amdgcn_s_setprio(0);
      }
      // per-pass epilogue: fold layer2 dot into rs
      #pragma unroll
      for (int t = 0; t < 4; ++t) {
        float4 l2v = *(const float4*)(lw2 + fcb + f*32 + t*8 + hi*4);
        #pragma unroll
        for (int e = 0; e < 4; ++e) {
          rs[e] += fmaxf(acc[e][4*t+0], 0.f) * l2v.x;
          rs[e] += fmaxf(acc[e][4*t+1], 0.f) * l2v.y;
          rs[e] += fmaxf(acc[e][4*t+2], 0.f) * l2v.z;
          rs[e] += fmaxf(acc[e][4*t+3], 0.f) * l2v.w;
        }
      }
    }
  }

  // ---- reduce + sigmoid ----
  {
    #pragma unroll
    for (int e = 0; e < 4; ++e) rs[e] += __shfl_xor(rs[e], 32, 64);
    float* red = (float*)e_lds;   // e tile dead (all waves past o0 barrier)
    if (hi == 0) {
      #pragma unroll
      for (int e = 0; e < 4; ++e) red[wv*BM + e*32 + l31] = rs[e];
    }
  }
  __syncthreads();

  if (tid < BM) {
    const float* red = (const float*)e_lds;
    float v = lb2[0];
    #pragma unroll
    for (int w = 0; w < 8; ++w) v += red[w*BM + tid];
    out[blk*BM + tid] = 1.0f / (1.0f + __expf(-v));
  }
}

// ---------------- launch ----------------
extern "C" void kernel_launch(void* const* d_in, const int* in_sizes, int n_in,
                              void* d_out, int out_size, void* d_ws, size_t ws_size,
                              hipStream_t stream) {
  const float* x      = (const float*)d_in[0];
  const float* wrel0  = (const float*)d_in[1];
  const float* brel0  = (const float*)d_in[2];
  const float* wroot0 = (const float*)d_in[3];
  const float* wrel1  = (const float*)d_in[4];
  const float* brel1  = (const float*)d_in[5];
  const float* wroot1 = (const float*)d_in[6];
  const float* lw0    = (const float*)d_in[7];
  const float* lb0    = (const float*)d_in[8];
  const float* lw1    = (const float*)d_in[9];
  const float* lb1    = (const float*)d_in[10];
  const float* lw2    = (const float*)d_in[11];
  const float* lb2    = (const float*)d_in[12];
  float* out = (float*)d_out;

  char* ws = (char*)d_ws;
  unsigned short* hb  = (unsigned short*)(ws);            // 1024*128 bf16 (262144 B)
  unsigned int*   w0q = (unsigned int*)(ws + 262144);     // W0 fp8 tiled (65536 B)
  unsigned int*   w1q = (unsigned int*)(ws + 327680);     // W1 fp8 tiled (262144 B)
  float* h0    = (float*)(ws + 589824);                   // 1024*128 f32 (524288 B)
  float* mean0 = (float*)(ws + 1114112);
  float* mean1 = (float*)(ws + 1114176);
  float* relc  = (float*)(ws + 1114688);

  hipLaunchKernelGGL(k_cvt_weights, dim3(320), dim3(256), 0, stream, lw0, lw1, w0q, w1q);
  hipLaunchKernelGGL(k_mean_x,   dim3(1),    dim3(256), 0, stream, x, mean0);
  hipLaunchKernelGGL(k_sage0,    dim3(512),  dim3(256), 0, stream, x, wrel0, brel0, wroot0, mean0, h0);
  hipLaunchKernelGGL(k_mean_h0,  dim3(128),  dim3(256), 0, stream, h0, mean1);
  hipLaunchKernelGGL(k_relc,     dim3(1),    dim3(128), 0, stream, mean1, wrel1, brel1, relc);
  hipLaunchKernelGGL(k_sage1,    dim3(512),  dim3(256), 0, stream, h0, wroot1, relc, hb);
  hipLaunchKernelGGL(k_edge_mlp, dim3(NEDGE/BM), dim3(512), 0, stream,
                     hb, w0q, lb0, w1q, lb1, lw2, lb2, out);
}

// Round 17
// 197.610 us; speedup vs baseline: 3.9553x; 3.9553x over previous
//
#include <hip/hip_runtime.h>
#include <hip/hip_bf16.h>
#include <math.h>

#define NN 1024
#define EMB 128
#define FC 512
#define NEDGE 523776   // 1024*1023/2
#define BM 64          // edge rows per block; 8184 blocks

typedef __attribute__((ext_vector_type(16))) float f32x16;
typedef __attribute__((ext_vector_type(8))) short bf16x8;
typedef __attribute__((ext_vector_type(4))) unsigned int u32x4;
typedef __attribute__((ext_vector_type(8))) int i32x8;

__device__ __forceinline__ float bf2f(unsigned short u) {
  union { unsigned int i; float f; } v; v.i = ((unsigned int)u) << 16; return v.f;
}
__device__ __forceinline__ unsigned short f2bf(float f) {
  return __builtin_bit_cast(unsigned short, __float2bfloat16(f));
}
__device__ __forceinline__ int cum_edges(int i) { return i * NN - ((i * (i + 1)) >> 1); }

// pack 4 f32 -> 4 fp8(e4m3 OCP) in one dword (bytes in order a,b,c,d)
__device__ __forceinline__ unsigned int pk4_fp8(float a, float b, float c, float d) {
  int v = __builtin_amdgcn_cvt_pk_fp8_f32(a, b, 0, false);
  v = __builtin_amdgcn_cvt_pk_fp8_f32(c, d, v, true);
  return (unsigned int)v;
}
// fp8 MFMA 32x32 K=64, uniform pow2 descale folded into the scale operand.
// L0: s=-9  (0x76...)  acc = 2^7 * preact  (o0 fp8 convention)
// L1: s=-13 (0x72...)  acc = true preact
#define MFMA32_L0(A,B,C) __builtin_amdgcn_mfma_scale_f32_32x32x64_f8f6f4((A),(B),(C),0,0,0,0x76767676,0,0x7f7f7f7f)
#define MFMA32_L1(A,B,C) __builtin_amdgcn_mfma_scale_f32_32x32x64_f8f6f4((A),(B),(C),0,0,0,0x72727272,0,0x7f7f7f7f)

// ---------------- setup kernels (tiny) ----------------
// fp8 weight tiles (x2^6) for 32x32x64 frags: lane holds row=lane&31,
// k-window = (lane>>5)*32 + [0..32) contiguous bytes.
// W0 dword d = wv*2048 + kb*1024 + f*512 + lane*8 + dw   (kb<2, f<2)
// W1 dword d = wv*8192 + kb*1024 + f*512 + lane*8 + dw   (kb<8, f<2)
__global__ void k_cvt_weights(const float* __restrict__ lw0, const float* __restrict__ lw1,
                              unsigned int* __restrict__ w0q, unsigned int* __restrict__ w1q) {
  int d = blockIdx.x * 256 + threadIdx.x;   // 320 blocks * 256 = 81920 dwords exact
  if (d < 16384) {
    int dw = d & 7, lane = (d >> 3) & 63, f = (d >> 9) & 1, kb = (d >> 10) & 1, wv = (d >> 11) & 7;
    int fc = wv*64 + f*32 + (lane & 31);
    int k  = kb*64 + (lane >> 5)*32 + dw*4;
    float4 s = *(const float4*)(lw0 + fc*EMB + k);
    w0q[d] = pk4_fp8(s.x*64.f, s.y*64.f, s.z*64.f, s.w*64.f);
  } else {
    int u = d - 16384;
    int dw = u & 7, lane = (u >> 3) & 63, f = (u >> 9) & 1, kb = (u >> 10) & 7, wv = (u >> 13) & 7;
    int fc = wv*64 + f*32 + (lane & 31);
    int k  = kb*64 + (lane >> 5)*32 + dw*4;
    float4 s = *(const float4*)(lw1 + fc*FC + k);
    w1q[u] = pk4_fp8(s.x*64.f, s.y*64.f, s.z*64.f, s.w*64.f);
  }
}

__global__ void k_mean_x(const float* __restrict__ x, float* __restrict__ mean0) {
  __shared__ float sx[256], sy[256];
  float ax = 0.f, ay = 0.f;
  for (int i = threadIdx.x; i < NN; i += 256) { ax += x[2*i]; ay += x[2*i+1]; }
  sx[threadIdx.x] = ax; sy[threadIdx.x] = ay;
  __syncthreads();
  for (int st = 128; st > 0; st >>= 1) {
    if (threadIdx.x < st) { sx[threadIdx.x] += sx[threadIdx.x+st]; sy[threadIdx.x] += sy[threadIdx.x+st]; }
    __syncthreads();
  }
  if (threadIdx.x == 0) { mean0[0] = sx[0] * (1.f/NN); mean0[1] = sy[0] * (1.f/NN); }
}

__global__ void k_sage0(const float* __restrict__ x, const float* __restrict__ wrel,
                        const float* __restrict__ brel, const float* __restrict__ wroot,
                        const float* __restrict__ mean0, float* __restrict__ h0) {
  int idx = blockIdx.x * 256 + threadIdx.x;
  int i = idx >> 7, c = idx & 127;
  float v = mean0[0]*wrel[2*c] + mean0[1]*wrel[2*c+1] + brel[c]
          + x[2*i]*wroot[2*c] + x[2*i+1]*wroot[2*c+1];
  h0[idx] = fmaxf(v, 0.f);
}

__global__ void k_mean_h0(const float* __restrict__ h0, float* __restrict__ mean1) {
  __shared__ float s[256];
  int c = blockIdx.x;
  float a = 0.f;
  for (int i = threadIdx.x; i < NN; i += 256) a += h0[i*EMB + c];
  s[threadIdx.x] = a;
  __syncthreads();
  for (int st = 128; st > 0; st >>= 1) {
    if (threadIdx.x < st) s[threadIdx.x] += s[threadIdx.x+st];
    __syncthreads();
  }
  if (threadIdx.x == 0) mean1[c] = s[0] * (1.f/NN);
}

__global__ void k_relc(const float* __restrict__ mean1, const float* __restrict__ wrel1,
                       const float* __restrict__ brel1, float* __restrict__ relc) {
  int c = threadIdx.x;
  float a = brel1[c];
  #pragma unroll 8
  for (int k = 0; k < EMB; ++k) a += mean1[k] * wrel1[c*EMB + k];
  relc[c] = a;
}

// hb pre-scaled by 32 -> edge products carry 2^10
__global__ void k_sage1(const float* __restrict__ h0, const float* __restrict__ wroot1,
                        const float* __restrict__ relc, unsigned short* __restrict__ hb) {
  int idx = blockIdx.x * 256 + threadIdx.x;
  int i = idx >> 7, c = idx & 127;
  const float4* hr = (const float4*)(h0 + i*EMB);
  const float4* wr = (const float4*)(wroot1 + c*EMB);
  float a = relc[c];
  #pragma unroll 8
  for (int k = 0; k < EMB/4; ++k) {
    float4 h = hr[k], w = wr[k];
    a += h.x*w.x + h.y*w.y + h.z*w.z + h.w*w.w;
  }
  hb[idx] = f2bf(fmaxf(a, 0.f) * 32.0f);
}

// ---------------- fused edge MLP (full fp8, 32x32x64 MFMA) ----------------
// 8 waves; wave w owns fc slice [w*64, w*64+64): 2 m-tiles of 32.
// Edges 64: 2 n-tiles of 32. A = weights (m=fc), B = activations (n=edge).
// D (32x32): col(edge)=lane&31, row(fc_local)=(rg&3)+8*(rg>>2)+4*(lane>>5).
// LDS activation layout SPLIT-HALF: [..][kb][half(2)][lane(64)][16B] so every
// ds_read_b128 has 16B lane stride (bank-conflict-minimal, r8-verified).
// i32x8 operands pieced from the two halves (r9-verified reg-safe pattern).
// Scales: e=2^10, W=2^6, o0=2^7; descales folded into MFMA scale operand.
// LDS 40KB; (512,4) -> 2+ blocks/CU.
__global__ __launch_bounds__(512, 4)
void k_edge_mlp(const unsigned short* __restrict__ hb,
                const unsigned int* __restrict__ w0q,
                const float* __restrict__ lb0,
                const unsigned int* __restrict__ w1q,
                const float* __restrict__ lb1,
                const float* __restrict__ lw2,
                const float* __restrict__ lb2,
                float* __restrict__ out) {
  __shared__ __align__(16) unsigned int e_lds[2048];    // 8 KB  [et2][kb2][half2][lane64][16B]
  __shared__ __align__(16) unsigned int o0_lds[8192];   // 32 KB [et2][kb8][half2][lane64][16B]

  const int tid  = threadIdx.x;
  const int lane = tid & 63;
  const int wv   = tid >> 6;           // 0..7
  const int l31  = lane & 31;
  const int hi   = lane >> 5;
  const int blk  = blockIdx.x;
  const int fcb  = wv * 64;

  const char* w0w = (const char*)w0q + wv * 8192;    // 8 KB/wave
  const char* w1w = (const char*)w1q + wv * 32768;   // 32 KB/wave

  // ---- Phase A: gather h rows, build e tile (fp8, split-half frag order) ----
  {
    int r = tid >> 3, q = tid & 7;     // edge row r, 16-byte k-chunk q
    int k = blk * BM + r;
    float s = sqrtf((float)(4190209 - 8*k));           // (2N-1)^2 - 8k
    int i = (int)((2047.0f - s) * 0.5f);
    if (i < 0) i = 0;
    if (i > NN-2) i = NN-2;
    if (cum_edges(i+1) <= k) ++i;
    if (cum_edges(i+1) <= k) ++i;
    if (cum_edges(i) > k) --i;
    if (cum_edges(i) > k) --i;
    int j = k - cum_edges(i) + i + 1;
    const bf16x8* hi8 = (const bf16x8*)(hb + i*EMB + q*16);
    const bf16x8* hj8 = (const bf16x8*)(hb + j*EMB + q*16);
    float p[16];
    #pragma unroll
    for (int g = 0; g < 2; ++g) {
      bf16x8 a = hi8[g], b = hj8[g];
      #pragma unroll
      for (int u = 0; u < 8; ++u)
        p[g*8+u] = bf2f((unsigned short)a[u]) * bf2f((unsigned short)b[u]);
    }
    u32x4 d;
    #pragma unroll
    for (int u = 0; u < 4; ++u)
      d[u] = pk4_fp8(p[4*u], p[4*u+1], p[4*u+2], p[4*u+3]);
    // dest: et=r>>5, kb=q>>2, half=q&1, lane'=((q>>1)&1)*32+(r&31)
    int byt = (r>>5)*4096 + (q>>2)*2048 + (q&1)*1024 + (((q>>1)&1)*32 + (r&31))*16;
    *(u32x4*)((char*)e_lds + byt) = d;
  }
  __syncthreads();

  f32x16 acc[2][2];

  // ---- Layer0: K=128 = 2 kb of 64; acc init = b0 * 2^7 ----
  #pragma unroll
  for (int f = 0; f < 2; ++f)
    #pragma unroll
    for (int t = 0; t < 4; ++t) {
      float4 bv = *(const float4*)(lb0 + fcb + f*32 + t*8 + hi*4);
      #pragma unroll
      for (int e = 0; e < 2; ++e) {
        acc[e][f][4*t+0] = bv.x*128.f; acc[e][f][4*t+1] = bv.y*128.f;
        acc[e][f][4*t+2] = bv.z*128.f; acc[e][f][4*t+3] = bv.w*128.f;
      }
    }
  {
    const char* rbe = (const char*)e_lds + lane*16;
    #pragma unroll
    for (int kb = 0; kb < 2; ++kb) {
      i32x8 a0 = *(const i32x8*)(w0w + (kb*2+0)*2048 + lane*32);
      i32x8 a1 = *(const i32x8*)(w0w + (kb*2+1)*2048 + lane*32);
      i32x8 b0, b1;
      *(u32x4*)&b0       = *(const u32x4*)(rbe + kb*2048);
      *((u32x4*)&b0 + 1) = *(const u32x4*)(rbe + kb*2048 + 1024);
      *(u32x4*)&b1       = *(const u32x4*)(rbe + 4096 + kb*2048);
      *((u32x4*)&b1 + 1) = *(const u32x4*)(rbe + 4096 + kb*2048 + 1024);
      __builtin_amdgcn_s_setprio(1);
      acc[0][0] = MFMA32_L0(a0, b0, acc[0][0]);
      acc[0][1] = MFMA32_L0(a1, b0, acc[0][1]);
      acc[1][0] = MFMA32_L0(a0, b1, acc[1][0]);
      acc[1][1] = MFMA32_L0(a1, b1, acc[1][1]);
      __builtin_amdgcn_s_setprio(0);
    }
  }

  // ---- relu + fp8 o0 store (acc already at 2^7 scale) ----
  // value(edge=e*32+l31, fc = fcb + f*32 + 8t + 4hi + j) ->
  //   et=e, kb=wv, half=t>>1, lane'=f*32+l31, byte=(t&1)*8 + hi*4
  {
    char* ob = (char*)o0_lds + wv*2048 + l31*16 + hi*4;
    #pragma unroll
    for (int f = 0; f < 2; ++f)
      #pragma unroll
      for (int e = 0; e < 2; ++e)
        #pragma unroll
        for (int t = 0; t < 4; ++t) {
          unsigned int d = pk4_fp8(fmaxf(acc[e][f][4*t+0], 0.f),
                                   fmaxf(acc[e][f][4*t+1], 0.f),
                                   fmaxf(acc[e][f][4*t+2], 0.f),
                                   fmaxf(acc[e][f][4*t+3], 0.f));
          *(unsigned int*)(ob + e*16384 + (t>>1)*1024 + f*512 + (t&1)*8) = d;
        }
  }
  __syncthreads();

  // ---- Layer1: K=512 = 8 kb of 64; acc init = b1 (true scale) ----
  #pragma unroll
  for (int f = 0; f < 2; ++f)
    #pragma unroll
    for (int t = 0; t < 4; ++t) {
      float4 bv = *(const float4*)(lb1 + fcb + f*32 + t*8 + hi*4);
      #pragma unroll
      for (int e = 0; e < 2; ++e) {
        acc[e][f][4*t+0] = bv.x; acc[e][f][4*t+1] = bv.y;
        acc[e][f][4*t+2] = bv.z; acc[e][f][4*t+3] = bv.w;
      }
    }
  {
    const char* rbo = (const char*)o0_lds + lane*16;
    #pragma unroll
    for (int kb = 0; kb < 8; ++kb) {
      i32x8 a0 = *(const i32x8*)(w1w + (kb*2+0)*2048 + lane*32);
      i32x8 a1 = *(const i32x8*)(w1w + (kb*2+1)*2048 + lane*32);
      i32x8 b0, b1;
      *(u32x4*)&b0       = *(const u32x4*)(rbo + kb*2048);
      *((u32x4*)&b0 + 1) = *(const u32x4*)(rbo + kb*2048 + 1024);
      *(u32x4*)&b1       = *(const u32x4*)(rbo + 16384 + kb*2048);
      *((u32x4*)&b1 + 1) = *(const u32x4*)(rbo + 16384 + kb*2048 + 1024);
      __builtin_amdgcn_s_setprio(1);
      acc[0][0] = MFMA32_L1(a0, b0, acc[0][0]);
      acc[0][1] = MFMA32_L1(a1, b0, acc[0][1]);
      acc[1][0] = MFMA32_L1(a0, b1, acc[1][0]);
      acc[1][1] = MFMA32_L1(a1, b1, acc[1][1]);
      __builtin_amdgcn_s_setprio(0);
    }
  }

  // ---- fused layer2 + sigmoid (acc at true scale, bias in init) ----
  {
    float rs0 = 0.f, rs1 = 0.f;
    #pragma unroll
    for (int f = 0; f < 2; ++f)
      #pragma unroll
      for (int t = 0; t < 4; ++t) {
        float4 l2v = *(const float4*)(lw2 + fcb + f*32 + t*8 + hi*4);
        rs0 += fmaxf(acc[0][f][4*t+0], 0.f) * l2v.x;
        rs0 += fmaxf(acc[0][f][4*t+1], 0.f) * l2v.y;
        rs0 += fmaxf(acc[0][f][4*t+2], 0.f) * l2v.z;
        rs0 += fmaxf(acc[0][f][4*t+3], 0.f) * l2v.w;
        rs1 += fmaxf(acc[1][f][4*t+0], 0.f) * l2v.x;
        rs1 += fmaxf(acc[1][f][4*t+1], 0.f) * l2v.y;
        rs1 += fmaxf(acc[1][f][4*t+2], 0.f) * l2v.z;
        rs1 += fmaxf(acc[1][f][4*t+3], 0.f) * l2v.w;
      }
    rs0 += __shfl_xor(rs0, 32, 64);
    rs1 += __shfl_xor(rs1, 32, 64);
    float* red = (float*)e_lds;   // e tile dead (all waves past o0 barrier)
    if (hi == 0) {
      red[wv*64 + l31]      = rs0;
      red[wv*64 + 32 + l31] = rs1;
    }
  }
  __syncthreads();

  if (tid < BM) {
    const float* red = (const float*)e_lds;
    float v = lb2[0];
    #pragma unroll
    for (int w = 0; w < 8; ++w) v += red[w*BM + tid];
    out[blk*BM + tid] = 1.0f / (1.0f + __expf(-v));
  }
}

// ---------------- launch ----------------
extern "C" void kernel_launch(void* const* d_in, const int* in_sizes, int n_in,
                              void* d_out, int out_size, void* d_ws, size_t ws_size,
                              hipStream_t stream) {
  const float* x      = (const float*)d_in[0];
  const float* wrel0  = (const float*)d_in[1];
  const float* brel0  = (const float*)d_in[2];
  const float* wroot0 = (const float*)d_in[3];
  const float* wrel1  = (const float*)d_in[4];
  const float* brel1  = (const float*)d_in[5];
  const float* wroot1 = (const float*)d_in[6];
  const float* lw0    = (const float*)d_in[7];
  const float* lb0    = (const float*)d_in[8];
  const float* lw1    = (const float*)d_in[9];
  const float* lb1    = (const float*)d_in[10];
  const float* lw2    = (const float*)d_in[11];
  const float* lb2    = (const float*)d_in[12];
  float* out = (float*)d_out;

  char* ws = (char*)d_ws;
  unsigned short* hb  = (unsigned short*)(ws);            // 1024*128 bf16 (262144 B)
  unsigned int*   w0q = (unsigned int*)(ws + 262144);     // W0 fp8 tiled (65536 B)
  unsigned int*   w1q = (unsigned int*)(ws + 327680);     // W1 fp8 tiled (262144 B)
  float* h0    = (float*)(ws + 589824);                   // 1024*128 f32 (524288 B)
  float* mean0 = (float*)(ws + 1114112);
  float* mean1 = (float*)(ws + 1114176);
  float* relc  = (float*)(ws + 1114688);

  hipLaunchKernelGGL(k_cvt_weights, dim3(320), dim3(256), 0, stream, lw0, lw1, w0q, w1q);
  hipLaunchKernelGGL(k_mean_x,   dim3(1),    dim3(256), 0, stream, x, mean0);
  hipLaunchKernelGGL(k_sage0,    dim3(512),  dim3(256), 0, stream, x, wrel0, brel0, wroot0, mean0, h0);
  hipLaunchKernelGGL(k_mean_h0,  dim3(128),  dim3(256), 0, stream, h0, mean1);
  hipLaunchKernelGGL(k_relc,     dim3(1),    dim3(128), 0, stream, mean1, wrel1, brel1, relc);
  hipLaunchKernelGGL(k_sage1,    dim3(512),  dim3(256), 0, stream, h0, wroot1, relc, hb);
  hipLaunchKernelGGL(k_edge_mlp, dim3(NEDGE/BM), dim3(512), 0, stream,
                     hb, w0q, lb0, w1q, lb1, lw2, lb2, out);
}